// Round 1
// baseline (1463.076 us; speedup 1.0000x reference)
//
#include <hip/hip_runtime.h>
#include <math.h>

#define N_NODES 50000
#define N_EDGES 800000
#define D 128

// ---------------------------------------------------------------------------
// deg[col[e]] += 1 for each edge
// ---------------------------------------------------------------------------
__global__ __launch_bounds__(256) void deg_kernel(const int* __restrict__ ei,
                                                  float* __restrict__ deg) {
    int e = blockIdx.x * blockDim.x + threadIdx.x;
    if (e < N_EDGES) {
        int col = ei[N_EDGES + e];
        atomicAdd(&deg[col], 1.0f);
    }
}

// ---------------------------------------------------------------------------
// dis[i] = deg[i] > 0 ? 1/sqrt(deg[i]) : 0
// ---------------------------------------------------------------------------
__global__ __launch_bounds__(256) void dis_kernel(const float* __restrict__ deg,
                                                  float* __restrict__ dis) {
    int i = blockIdx.x * blockDim.x + threadIdx.x;
    if (i < N_NODES) {
        float d = deg[i];
        dis[i] = (d > 0.0f) ? (1.0f / sqrtf(d)) : 0.0f;
    }
}

// ---------------------------------------------------------------------------
// h_mean = x @ Wm^T + bm ; h_std = x @ Ws^T + bs
// Writes h into workspace (stable gather source) AND into d_out (residual init).
// Block: 256 threads = (m in {0,1}) x (c in 0..127); TILE_R=32 rows per block.
// ---------------------------------------------------------------------------
#define TILE_R 32
__global__ __launch_bounds__(256) void gemm_kernel(
    const float* __restrict__ x,
    const float* __restrict__ Wm, const float* __restrict__ bm,
    const float* __restrict__ Ws, const float* __restrict__ bs,
    float* __restrict__ h, float* __restrict__ out)
{
    __shared__ float xs[TILE_R][D];
    const int r0 = blockIdx.x * TILE_R;
    const int tid = threadIdx.x;

    // stage x tile: TILE_R*D floats, float4-vectorized, coalesced
    for (int i = tid; i < TILE_R * D / 4; i += 256) {
        int rr = i / (D / 4);
        int cc = (i % (D / 4)) * 4;
        int r = r0 + rr;
        float4 v = make_float4(0.f, 0.f, 0.f, 0.f);
        if (r < N_NODES) v = *(const float4*)(x + (size_t)r * D + cc);
        *(float4*)(&xs[rr][cc]) = v;
    }
    __syncthreads();

    const int m = tid >> 7;       // 0 = mean, 1 = std
    const int c = tid & 127;      // output column
    const float* __restrict__ W = m ? Ws : Wm;
    const float bias = m ? bs[c] : bm[c];

    float acc[TILE_R];
#pragma unroll
    for (int rr = 0; rr < TILE_R; ++rr) acc[rr] = bias;

    for (int kc = 0; kc < D; kc += 32) {
        float w[32];
#pragma unroll
        for (int j = 0; j < 32; j += 4) {
            float4 v = *(const float4*)(W + (size_t)c * D + kc + j);
            w[j] = v.x; w[j + 1] = v.y; w[j + 2] = v.z; w[j + 3] = v.w;
        }
#pragma unroll
        for (int rr = 0; rr < TILE_R; ++rr) {
#pragma unroll
            for (int j = 0; j < 32; j += 4) {
                float4 xv = *(const float4*)(&xs[rr][kc + j]);  // uniform addr -> LDS broadcast
                acc[rr] = fmaf(xv.x, w[j],     acc[rr]);
                acc[rr] = fmaf(xv.y, w[j + 1], acc[rr]);
                acc[rr] = fmaf(xv.z, w[j + 2], acc[rr]);
                acc[rr] = fmaf(xv.w, w[j + 3], acc[rr]);
            }
        }
    }

    const size_t base = (size_t)m * N_NODES * D;
#pragma unroll
    for (int rr = 0; rr < TILE_R; ++rr) {
        int r = r0 + rr;
        if (r < N_NODES) {
            size_t off = base + (size_t)r * D + c;
            h[off] = acc[rr];
            out[off] = acc[rr];   // residual: out starts at h, edges accumulate on top
        }
    }
}

// ---------------------------------------------------------------------------
// Edge pass, fused over both branches (reads edge_attr ONCE):
//   norm = dis[row]*dis[col]
//   out_m[col] += norm*(h_m[row] + ea);  out_s[col] += norm*(h_s[row] + ea)
// One wave (64 lanes) per edge, 2 floats per lane (D=128).
// ---------------------------------------------------------------------------
__global__ __launch_bounds__(256) void edge_kernel(
    const int* __restrict__ ei, const float* __restrict__ ea,
    const float* __restrict__ dis,
    const float* __restrict__ hm, const float* __restrict__ hs,
    float* __restrict__ om, float* __restrict__ os)
{
    const int lane = threadIdx.x & 63;
    const int wave = (int)((blockIdx.x * blockDim.x + threadIdx.x) >> 6);
    const int nwaves = (int)((gridDim.x * (size_t)blockDim.x) >> 6);
    const int k = lane * 2;

    for (int e = wave; e < N_EDGES; e += nwaves) {
        int row = ei[e];
        int col = ei[N_EDGES + e];
        float norm = dis[row] * dis[col];

        float2 eav = *(const float2*)(ea + (size_t)e * D + k);
        float2 hmv = *(const float2*)(hm + (size_t)row * D + k);
        float2 hsv = *(const float2*)(hs + (size_t)row * D + k);

        size_t ob = (size_t)col * D + k;
        atomicAdd(&om[ob],     norm * (hmv.x + eav.x));
        atomicAdd(&om[ob + 1], norm * (hmv.y + eav.y));
        atomicAdd(&os[ob],     norm * (hsv.x + eav.x));
        atomicAdd(&os[ob + 1], norm * (hsv.y + eav.y));
    }
}

extern "C" void kernel_launch(void* const* d_in, const int* in_sizes, int n_in,
                              void* d_out, int out_size, void* d_ws, size_t ws_size,
                              hipStream_t stream) {
    const float* x   = (const float*)d_in[0];
    const int*   ei  = (const int*)d_in[1];     // [2, E] int32
    const float* ea  = (const float*)d_in[2];   // [E, D]
    const float* Wm  = (const float*)d_in[3];
    const float* bm  = (const float*)d_in[4];
    const float* Ws  = (const float*)d_in[5];
    const float* bs  = (const float*)d_in[6];
    float* out = (float*)d_out;                 // [2, N, D] (mean, std)

    // workspace layout
    float* ws  = (float*)d_ws;
    float* deg = ws;                      // N floats
    float* dis = ws + N_NODES;            // N floats
    float* h   = ws + 2 * N_NODES;        // 2*N*D floats (h_mean, h_std)
    float* hm  = h;
    float* hs  = h + (size_t)N_NODES * D;

    float* om = out;
    float* os = out + (size_t)N_NODES * D;

    // 1. zero degree accumulator (ws is poisoned, not re-poisoned between replays)
    hipMemsetAsync(deg, 0, N_NODES * sizeof(float), stream);

    // 2. degree
    deg_kernel<<<(N_EDGES + 255) / 256, 256, 0, stream>>>(ei, deg);

    // 3. deg^{-1/2}
    dis_kernel<<<(N_NODES + 255) / 256, 256, 0, stream>>>(deg, dis);

    // 4. linear projections (writes h to ws and d_out)
    gemm_kernel<<<(N_NODES + TILE_R - 1) / TILE_R, 256, 0, stream>>>(
        x, Wm, bm, Ws, bs, h, out);

    // 5. fused edge scatter for both branches
    edge_kernel<<<16384, 256, 0, stream>>>(ei, ea, dis, hm, hs, om, os);
}

// Round 2
// 459.198 us; speedup vs baseline: 3.1862x; 3.1862x over previous
//
#include <hip/hip_runtime.h>
#include <math.h>

#define N_NODES 50000
#define N_EDGES 800000
#define D 128

// ---------------------------------------------------------------------------
// count[col[e]]++  (int histogram of destination nodes)
// ---------------------------------------------------------------------------
__global__ __launch_bounds__(256) void hist_kernel(const int* __restrict__ ei,
                                                   int* __restrict__ count) {
    int e = blockIdx.x * blockDim.x + threadIdx.x;
    if (e < N_EDGES) {
        atomicAdd(&count[ei[N_EDGES + e]], 1);
    }
}

// ---------------------------------------------------------------------------
// Single-block exclusive prefix scan of count[0..N) -> offset, cur (scatter
// cursors), plus dis[i] = count>0 ? rsqrt(count) : 0.
// 1024 threads = 16 waves; wave-scan via shfl, serial 16-way combine.
// ---------------------------------------------------------------------------
__global__ __launch_bounds__(1024) void scan_kernel(const int* __restrict__ count,
                                                    int* __restrict__ offset,
                                                    int* __restrict__ cur,
                                                    float* __restrict__ dis) {
    __shared__ int wsum[16];
    __shared__ int carry_s;
    const int tid = threadIdx.x;
    const int lane = tid & 63;
    const int wid = tid >> 6;
    if (tid == 0) carry_s = 0;
    __syncthreads();

    for (int base = 0; base < N_NODES; base += 1024) {
        int i = base + tid;
        int c = (i < N_NODES) ? count[i] : 0;
        int inc = c;
#pragma unroll
        for (int d = 1; d < 64; d <<= 1) {
            int v = __shfl_up(inc, d, 64);
            if (lane >= d) inc += v;
        }
        if (lane == 63) wsum[wid] = inc;
        __syncthreads();
        if (tid == 0) {
            int pre = carry_s;
#pragma unroll
            for (int w = 0; w < 16; ++w) { int t = wsum[w]; wsum[w] = pre; pre += t; }
            carry_s = pre;
        }
        __syncthreads();
        int exc = wsum[wid] + inc - c;   // exclusive prefix
        if (i < N_NODES) {
            offset[i] = exc;
            cur[i] = exc;
            dis[i] = (c > 0) ? rsqrtf((float)c) : 0.0f;
        }
        __syncthreads();   // protect wsum/carry_s for next chunk
    }
}

// ---------------------------------------------------------------------------
// Counting-sort scatter: eid[ cur[col]++ ] = e
// ---------------------------------------------------------------------------
__global__ __launch_bounds__(256) void scatter_kernel(const int* __restrict__ ei,
                                                      int* __restrict__ cur,
                                                      int* __restrict__ eid) {
    int e = blockIdx.x * blockDim.x + threadIdx.x;
    if (e < N_EDGES) {
        int col = ei[N_EDGES + e];
        int p = atomicAdd(&cur[col], 1);
        eid[p] = e;
    }
}

// ---------------------------------------------------------------------------
// h_mean = x @ Wm^T + bm ; h_std = x @ Ws^T + bs  -> workspace only.
// Block: 256 threads = (m in {0,1}) x (c in 0..127); TILE_R=32 rows per block.
// ---------------------------------------------------------------------------
#define TILE_R 32
__global__ __launch_bounds__(256) void gemm_kernel(
    const float* __restrict__ x,
    const float* __restrict__ Wm, const float* __restrict__ bm,
    const float* __restrict__ Ws, const float* __restrict__ bs,
    float* __restrict__ h)
{
    __shared__ float xs[TILE_R][D];
    const int r0 = blockIdx.x * TILE_R;
    const int tid = threadIdx.x;

    for (int i = tid; i < TILE_R * D / 4; i += 256) {
        int rr = i / (D / 4);
        int cc = (i % (D / 4)) * 4;
        int r = r0 + rr;
        float4 v = make_float4(0.f, 0.f, 0.f, 0.f);
        if (r < N_NODES) v = *(const float4*)(x + (size_t)r * D + cc);
        *(float4*)(&xs[rr][cc]) = v;
    }
    __syncthreads();

    const int m = tid >> 7;       // 0 = mean, 1 = std
    const int c = tid & 127;      // output column
    const float* __restrict__ W = m ? Ws : Wm;
    const float bias = m ? bs[c] : bm[c];

    float acc[TILE_R];
#pragma unroll
    for (int rr = 0; rr < TILE_R; ++rr) acc[rr] = bias;

    for (int kc = 0; kc < D; kc += 32) {
        float w[32];
#pragma unroll
        for (int j = 0; j < 32; j += 4) {
            float4 v = *(const float4*)(W + (size_t)c * D + kc + j);
            w[j] = v.x; w[j + 1] = v.y; w[j + 2] = v.z; w[j + 3] = v.w;
        }
#pragma unroll
        for (int rr = 0; rr < TILE_R; ++rr) {
#pragma unroll
            for (int j = 0; j < 32; j += 4) {
                float4 xv = *(const float4*)(&xs[rr][kc + j]);  // LDS broadcast
                acc[rr] = fmaf(xv.x, w[j],     acc[rr]);
                acc[rr] = fmaf(xv.y, w[j + 1], acc[rr]);
                acc[rr] = fmaf(xv.z, w[j + 2], acc[rr]);
                acc[rr] = fmaf(xv.w, w[j + 3], acc[rr]);
            }
        }
    }

    const size_t base = (size_t)m * N_NODES * D;
#pragma unroll
    for (int rr = 0; rr < TILE_R; ++rr) {
        int r = r0 + rr;
        if (r < N_NODES) h[base + (size_t)r * D + c] = acc[rr];
    }
}

// ---------------------------------------------------------------------------
// CSR aggregation: one block (128 threads, thread = column) per node.
//   out_m[n] = hm[n] + dis[n] * sum_{e in in(n)} dis[row_e] * (hm[row_e] + ea[e])
//   out_s[n] = hs[n] + dis[n] * sum_{e in in(n)} dis[row_e] * (hs[row_e] + ea[e])
// No atomics: node n is owned exclusively by block n; single coalesced write.
// ---------------------------------------------------------------------------
__global__ __launch_bounds__(128) void agg_kernel(
    const int* __restrict__ ei, const float* __restrict__ ea,
    const int* __restrict__ eid,
    const int* __restrict__ offset, const int* __restrict__ count,
    const float* __restrict__ dis,
    const float* __restrict__ hm, const float* __restrict__ hs,
    float* __restrict__ om, float* __restrict__ os)
{
    const int n = blockIdx.x;
    const int c = threadIdx.x;

    const int start = offset[n];
    const int cnt = count[n];
    const float dc = dis[n];

    float am = 0.0f, as = 0.0f;
    for (int j = 0; j < cnt; ++j) {
        int e = eid[start + j];          // uniform across block -> broadcast
        int row = ei[e];                 // uniform -> broadcast
        float dr = dis[row];             // uniform -> broadcast
        float eav = ea[(size_t)e * D + c];         // 512B coalesced row
        am += dr * (hm[(size_t)row * D + c] + eav);
        as += dr * (hs[(size_t)row * D + c] + eav);
    }

    size_t ob = (size_t)n * D + c;
    om[ob] = hm[ob] + dc * am;
    os[ob] = hs[ob] + dc * as;
}

extern "C" void kernel_launch(void* const* d_in, const int* in_sizes, int n_in,
                              void* d_out, int out_size, void* d_ws, size_t ws_size,
                              hipStream_t stream) {
    const float* x   = (const float*)d_in[0];
    const int*   ei  = (const int*)d_in[1];     // [2, E] int32
    const float* ea  = (const float*)d_in[2];   // [E, D]
    const float* Wm  = (const float*)d_in[3];
    const float* bm  = (const float*)d_in[4];
    const float* Ws  = (const float*)d_in[5];
    const float* bs  = (const float*)d_in[6];
    float* out = (float*)d_out;                 // [2, N, D]

    // workspace layout (all 16B-aligned by construction)
    char* w = (char*)d_ws;
    int*   count  = (int*)w;                          w += N_NODES * 4;
    int*   cur    = (int*)w;                          w += N_NODES * 4;
    int*   offset = (int*)w;                          w += N_NODES * 4;
    float* dis    = (float*)w;                        w += N_NODES * 4;
    int*   eid    = (int*)w;                          w += N_EDGES * 4;
    float* h      = (float*)w;                        // 2*N*D floats
    float* hm = h;
    float* hs = h + (size_t)N_NODES * D;

    float* om = out;
    float* os = out + (size_t)N_NODES * D;

    // 1. zero histogram (ws is poisoned once, never re-poisoned)
    hipMemsetAsync(count, 0, N_NODES * sizeof(int), stream);

    // 2. histogram of destinations
    hist_kernel<<<(N_EDGES + 255) / 256, 256, 0, stream>>>(ei, count);

    // 3. prefix scan -> offsets + cursors, and dis = rsqrt(deg)
    scan_kernel<<<1, 1024, 0, stream>>>(count, offset, cur, dis);

    // 4. counting-sort scatter of edge ids by destination node
    scatter_kernel<<<(N_EDGES + 255) / 256, 256, 0, stream>>>(ei, cur, eid);

    // 5. linear projections -> h (workspace)
    gemm_kernel<<<(N_NODES + TILE_R - 1) / TILE_R, 256, 0, stream>>>(
        x, Wm, bm, Ws, bs, h);

    // 6. atomic-free CSR aggregation, fused residual + both branches
    agg_kernel<<<N_NODES, 128, 0, stream>>>(ei, ea, eid, offset, count, dis,
                                            hm, hs, om, os);
}

// Round 3
// 374.820 us; speedup vs baseline: 3.9034x; 1.2251x over previous
//
#include <hip/hip_runtime.h>
#include <math.h>

#define N_NODES 50000
#define N_EDGES 800000
#define D 128

// ---------------------------------------------------------------------------
// zero the histogram (ws is poisoned 0xAA once, never re-poisoned)
// ---------------------------------------------------------------------------
__global__ __launch_bounds__(256) void zero_kernel(int* __restrict__ p, int n) {
    int i = blockIdx.x * blockDim.x + threadIdx.x;
    if (i < n) p[i] = 0;
}

// ---------------------------------------------------------------------------
// count[col[e]]++  (int histogram of destination nodes)
// ---------------------------------------------------------------------------
__global__ __launch_bounds__(256) void hist_kernel(const int* __restrict__ ei,
                                                   int* __restrict__ count) {
    int e = blockIdx.x * blockDim.x + threadIdx.x;
    if (e < N_EDGES) {
        atomicAdd(&count[ei[N_EDGES + e]], 1);
    }
}

// ---------------------------------------------------------------------------
// scan1: per-block (1024-element) exclusive scan of count -> offset (local),
// block totals -> bsum, and dis = rsqrt(count) fused in.
// ---------------------------------------------------------------------------
__global__ __launch_bounds__(1024) void scan1_kernel(const int* __restrict__ count,
                                                     int* __restrict__ offset,
                                                     float* __restrict__ dis,
                                                     int* __restrict__ bsum) {
    __shared__ int wsum[16];
    const int tid = threadIdx.x;
    const int lane = tid & 63;
    const int wid = tid >> 6;
    const int i = blockIdx.x * 1024 + tid;

    int c = (i < N_NODES) ? count[i] : 0;
    int inc = c;
#pragma unroll
    for (int d = 1; d < 64; d <<= 1) {
        int v = __shfl_up(inc, d, 64);
        if (lane >= d) inc += v;
    }
    if (lane == 63) wsum[wid] = inc;
    __syncthreads();
    if (wid == 0) {
        int s = (lane < 16) ? wsum[lane] : 0;
#pragma unroll
        for (int d = 1; d < 16; d <<= 1) {
            int v = __shfl_up(s, d, 64);
            if (lane >= d) s += v;
        }
        if (lane < 16) wsum[lane] = s;   // inclusive wave-prefix
    }
    __syncthreads();
    int wpre = (wid > 0) ? wsum[wid - 1] : 0;
    if (i < N_NODES) {
        offset[i] = wpre + inc - c;       // block-local exclusive prefix
        dis[i] = (c > 0) ? rsqrtf((float)c) : 0.0f;
    }
    if (tid == 0) bsum[blockIdx.x] = wsum[15];
}

// ---------------------------------------------------------------------------
// fixup: offset[i] += sum(bsum[0..blk)); cur[i] = offset[i]
// ---------------------------------------------------------------------------
__global__ __launch_bounds__(1024) void fixup_kernel(const int* __restrict__ bsum,
                                                     int* __restrict__ offset,
                                                     int* __restrict__ cur) {
    __shared__ int pre_s;
    const int tid = threadIdx.x;
    const int blk = blockIdx.x;
    if ((tid >> 6) == 0) {
        int lane = tid & 63;
        int s = 0;
        for (int j = lane; j < blk; j += 64) s += bsum[j];
#pragma unroll
        for (int d = 32; d > 0; d >>= 1) s += __shfl_xor(s, d, 64);
        if (lane == 0) pre_s = s;
    }
    __syncthreads();
    int i = blk * 1024 + tid;
    if (i < N_NODES) {
        int o = offset[i] + pre_s;
        offset[i] = o;
        cur[i] = o;
    }
}

// ---------------------------------------------------------------------------
// Counting-sort scatter of packed per-edge metadata, grouped by destination:
//   meta[p] = { e, row, bitcast(dis[row]), 0 }
// ---------------------------------------------------------------------------
__global__ __launch_bounds__(256) void scatter_kernel(const int* __restrict__ ei,
                                                      const float* __restrict__ dis,
                                                      int* __restrict__ cur,
                                                      int4* __restrict__ meta) {
    int e = blockIdx.x * blockDim.x + threadIdx.x;
    if (e < N_EDGES) {
        int row = ei[e];
        int col = ei[N_EDGES + e];
        int p = atomicAdd(&cur[col], 1);
        meta[p] = make_int4(e, row, __float_as_int(dis[row]), 0);
    }
}

// ---------------------------------------------------------------------------
// h_mean = x @ Wm^T + bm ; h_std = x @ Ws^T + bs  -> workspace only.
// Block: 256 threads = (m in {0,1}) x (c in 0..127); TILE_R=32 rows per block.
// ---------------------------------------------------------------------------
#define TILE_R 32
__global__ __launch_bounds__(256) void gemm_kernel(
    const float* __restrict__ x,
    const float* __restrict__ Wm, const float* __restrict__ bm,
    const float* __restrict__ Ws, const float* __restrict__ bs,
    float* __restrict__ h)
{
    __shared__ float xs[TILE_R][D];
    const int r0 = blockIdx.x * TILE_R;
    const int tid = threadIdx.x;

    for (int i = tid; i < TILE_R * D / 4; i += 256) {
        int rr = i / (D / 4);
        int cc = (i % (D / 4)) * 4;
        int r = r0 + rr;
        float4 v = make_float4(0.f, 0.f, 0.f, 0.f);
        if (r < N_NODES) v = *(const float4*)(x + (size_t)r * D + cc);
        *(float4*)(&xs[rr][cc]) = v;
    }
    __syncthreads();

    const int m = tid >> 7;       // 0 = mean, 1 = std
    const int c = tid & 127;      // output column
    const float* __restrict__ W = m ? Ws : Wm;
    const float bias = m ? bs[c] : bm[c];

    float acc[TILE_R];
#pragma unroll
    for (int rr = 0; rr < TILE_R; ++rr) acc[rr] = bias;

    for (int kc = 0; kc < D; kc += 32) {
        float w[32];
#pragma unroll
        for (int j = 0; j < 32; j += 4) {
            float4 v = *(const float4*)(W + (size_t)c * D + kc + j);
            w[j] = v.x; w[j + 1] = v.y; w[j + 2] = v.z; w[j + 3] = v.w;
        }
#pragma unroll
        for (int rr = 0; rr < TILE_R; ++rr) {
#pragma unroll
            for (int j = 0; j < 32; j += 4) {
                float4 xv = *(const float4*)(&xs[rr][kc + j]);  // LDS broadcast
                acc[rr] = fmaf(xv.x, w[j],     acc[rr]);
                acc[rr] = fmaf(xv.y, w[j + 1], acc[rr]);
                acc[rr] = fmaf(xv.z, w[j + 2], acc[rr]);
                acc[rr] = fmaf(xv.w, w[j + 3], acc[rr]);
            }
        }
    }

    const size_t base = (size_t)m * N_NODES * D;
#pragma unroll
    for (int rr = 0; rr < TILE_R; ++rr) {
        int r = r0 + rr;
        if (r < N_NODES) h[base + (size_t)r * D + c] = acc[rr];
    }
}

// ---------------------------------------------------------------------------
// CSR aggregation: ONE WAVE per node, lane = float2 column pair.
// Edge metadata loaded 64-edges-at-a-time per-lane, broadcast via v_readlane
// (no load-issue cost per edge). Per edge the wave issues exactly 3 vector
// loads (ea, hm, hs rows; 512B each, fully coalesced). No atomics.
//   out_m[n] = hm[n] + dis[n] * sum_e dr_e * (hm[row_e] + ea[e])
// ---------------------------------------------------------------------------
__global__ __launch_bounds__(256) void agg_kernel(
    const float* __restrict__ ea, const int4* __restrict__ meta,
    const int* __restrict__ offset, const int* __restrict__ cur,
    const float* __restrict__ dis,
    const float* __restrict__ hm, const float* __restrict__ hs,
    float* __restrict__ om, float* __restrict__ os)
{
    const int tid = threadIdx.x;
    const int lane = tid & 63;
    const int wid = tid >> 6;
    const int n = __builtin_amdgcn_readfirstlane(blockIdx.x * 4 + wid);

    const int start = offset[n];
    const int end = cur[n];          // after scatter, cur[n] == segment end
    const float dc = dis[n];
    const int k = lane * 2;

    float amx = 0.f, amy = 0.f, asx = 0.f, asy = 0.f;

    for (int jb = start; jb < end; jb += 64) {
        int4 mt = make_int4(0, 0, 0, 0);
        if (jb + lane < end) mt = meta[jb + lane];
        const int m = min(64, end - jb);
        for (int j = 0; j < m; ++j) {
            int e    = __builtin_amdgcn_readlane(mt.x, j);
            int row  = __builtin_amdgcn_readlane(mt.y, j);
            float dr = __int_as_float(__builtin_amdgcn_readlane(mt.z, j));

            float2 eav = *(const float2*)(ea + (size_t)e * D + k);
            float2 hmv = *(const float2*)(hm + (size_t)row * D + k);
            float2 hsv = *(const float2*)(hs + (size_t)row * D + k);

            amx = fmaf(dr, hmv.x + eav.x, amx);
            amy = fmaf(dr, hmv.y + eav.y, amy);
            asx = fmaf(dr, hsv.x + eav.x, asx);
            asy = fmaf(dr, hsv.y + eav.y, asy);
        }
    }

    const size_t ob = (size_t)n * D + k;
    float2 hmn = *(const float2*)(hm + ob);
    float2 hsn = *(const float2*)(hs + ob);
    float2 o0, o1;
    o0.x = hmn.x + dc * amx;  o0.y = hmn.y + dc * amy;
    o1.x = hsn.x + dc * asx;  o1.y = hsn.y + dc * asy;
    *(float2*)(om + ob) = o0;
    *(float2*)(os + ob) = o1;
}

extern "C" void kernel_launch(void* const* d_in, const int* in_sizes, int n_in,
                              void* d_out, int out_size, void* d_ws, size_t ws_size,
                              hipStream_t stream) {
    const float* x   = (const float*)d_in[0];
    const int*   ei  = (const int*)d_in[1];     // [2, E] int32
    const float* ea  = (const float*)d_in[2];   // [E, D]
    const float* Wm  = (const float*)d_in[3];
    const float* bm  = (const float*)d_in[4];
    const float* Ws  = (const float*)d_in[5];
    const float* bs  = (const float*)d_in[6];
    float* out = (float*)d_out;                 // [2, N, D]

    // workspace layout (16B-aligned chunks)
    char* w = (char*)d_ws;
    int*   count  = (int*)w;     w += (size_t)N_NODES * 4;   // 200000
    int*   offset = (int*)w;     w += (size_t)N_NODES * 4;
    int*   cur    = (int*)w;     w += (size_t)N_NODES * 4;
    float* dis    = (float*)w;   w += (size_t)N_NODES * 4;
    int*   bsum   = (int*)w;     w += 1024;                  // 49 used, padded
    int4*  meta   = (int4*)w;    w += (size_t)N_EDGES * 16;  // 12.8 MB
    float* h      = (float*)w;                               // 2*N*D floats
    float* hm = h;
    float* hs = h + (size_t)N_NODES * D;

    float* om = out;
    float* os = out + (size_t)N_NODES * D;

    const int SCAN_BLKS = (N_NODES + 1023) / 1024;   // 49

    // 1. zero histogram
    zero_kernel<<<(N_NODES + 255) / 256, 256, 0, stream>>>(count, N_NODES);

    // 2. histogram of destinations
    hist_kernel<<<(N_EDGES + 255) / 256, 256, 0, stream>>>(ei, count);

    // 3-4. parallel exclusive scan (+ dis = rsqrt(deg) fused)
    scan1_kernel<<<SCAN_BLKS, 1024, 0, stream>>>(count, offset, dis, bsum);
    fixup_kernel<<<SCAN_BLKS, 1024, 0, stream>>>(bsum, offset, cur);

    // 5. counting-sort scatter of packed edge metadata
    scatter_kernel<<<(N_EDGES + 255) / 256, 256, 0, stream>>>(ei, dis, cur, meta);

    // 6. linear projections -> h (workspace)
    gemm_kernel<<<(N_NODES + TILE_R - 1) / TILE_R, 256, 0, stream>>>(
        x, Wm, bm, Ws, bs, h);

    // 7. atomic-free CSR aggregation: one wave per node
    agg_kernel<<<N_NODES / 4, 256, 0, stream>>>(ea, meta, offset, cur, dis,
                                                hm, hs, om, os);
}

// Round 4
// 301.094 us; speedup vs baseline: 4.8592x; 1.2449x over previous
//
#include <hip/hip_runtime.h>
#include <math.h>

#define N_NODES 50000
#define N_EDGES 800000
#define D 128

// round-to-nearest-even fp32 -> bf16 (values are finite)
static __device__ __forceinline__ unsigned short f2bf(float f) {
    unsigned u = __float_as_uint(f);
    u += 0x7FFFu + ((u >> 16) & 1u);
    return (unsigned short)(u >> 16);
}

// ---------------------------------------------------------------------------
// zero the histogram (ws is poisoned 0xAA once, never re-poisoned)
// ---------------------------------------------------------------------------
__global__ __launch_bounds__(256) void zero_kernel(int* __restrict__ p, int n) {
    int i = blockIdx.x * blockDim.x + threadIdx.x;
    if (i < n) p[i] = 0;
}

// ---------------------------------------------------------------------------
// count[col[e]]++  (int histogram of destination nodes)
// ---------------------------------------------------------------------------
__global__ __launch_bounds__(256) void hist_kernel(const int* __restrict__ ei,
                                                   int* __restrict__ count) {
    int e = blockIdx.x * blockDim.x + threadIdx.x;
    if (e < N_EDGES) {
        atomicAdd(&count[ei[N_EDGES + e]], 1);
    }
}

// ---------------------------------------------------------------------------
// scan1: per-block (1024-element) exclusive scan of count -> offset (local),
// block totals -> bsum, and dis = rsqrt(count) fused in.
// ---------------------------------------------------------------------------
__global__ __launch_bounds__(1024) void scan1_kernel(const int* __restrict__ count,
                                                     int* __restrict__ offset,
                                                     float* __restrict__ dis,
                                                     int* __restrict__ bsum) {
    __shared__ int wsum[16];
    const int tid = threadIdx.x;
    const int lane = tid & 63;
    const int wid = tid >> 6;
    const int i = blockIdx.x * 1024 + tid;

    int c = (i < N_NODES) ? count[i] : 0;
    int inc = c;
#pragma unroll
    for (int d = 1; d < 64; d <<= 1) {
        int v = __shfl_up(inc, d, 64);
        if (lane >= d) inc += v;
    }
    if (lane == 63) wsum[wid] = inc;
    __syncthreads();
    if (wid == 0) {
        int s = (lane < 16) ? wsum[lane] : 0;
#pragma unroll
        for (int d = 1; d < 16; d <<= 1) {
            int v = __shfl_up(s, d, 64);
            if (lane >= d) s += v;
        }
        if (lane < 16) wsum[lane] = s;   // inclusive wave-prefix
    }
    __syncthreads();
    int wpre = (wid > 0) ? wsum[wid - 1] : 0;
    if (i < N_NODES) {
        offset[i] = wpre + inc - c;       // block-local exclusive prefix
        dis[i] = (c > 0) ? rsqrtf((float)c) : 0.0f;
    }
    if (tid == 0) bsum[blockIdx.x] = wsum[15];
}

// ---------------------------------------------------------------------------
// fixup: offset[i] += sum(bsum[0..blk)); cur[i] = offset[i]
// ---------------------------------------------------------------------------
__global__ __launch_bounds__(1024) void fixup_kernel(const int* __restrict__ bsum,
                                                     int* __restrict__ offset,
                                                     int* __restrict__ cur) {
    __shared__ int pre_s;
    const int tid = threadIdx.x;
    const int blk = blockIdx.x;
    if ((tid >> 6) == 0) {
        int lane = tid & 63;
        int s = 0;
        for (int j = lane; j < blk; j += 64) s += bsum[j];
#pragma unroll
        for (int d = 32; d > 0; d >>= 1) s += __shfl_xor(s, d, 64);
        if (lane == 0) pre_s = s;
    }
    __syncthreads();
    int i = blk * 1024 + tid;
    if (i < N_NODES) {
        int o = offset[i] + pre_s;
        offset[i] = o;
        cur[i] = o;
    }
}

// ---------------------------------------------------------------------------
// Counting-sort scatter of packed per-edge metadata, grouped by destination:
//   meta[p] = { e, row, bitcast(dis[row]), 0 }
// ---------------------------------------------------------------------------
__global__ __launch_bounds__(256) void scatter_kernel(const int* __restrict__ ei,
                                                      const float* __restrict__ dis,
                                                      int* __restrict__ cur,
                                                      int4* __restrict__ meta) {
    int e = blockIdx.x * blockDim.x + threadIdx.x;
    if (e < N_EDGES) {
        int row = ei[e];
        int col = ei[N_EDGES + e];
        int p = atomicAdd(&cur[col], 1);
        meta[p] = make_int4(e, row, __float_as_int(dis[row]), 0);
    }
}

// ---------------------------------------------------------------------------
// h_mean = x @ Wm^T + bm ; h_std = x @ Ws^T + bs.
// Writes fp32 h (residual source) AND packed bf16 hpk (gather source):
//   hpk byte layout per row: k=0..63 : {hm[2k],hm[2k+1],hs[2k],hs[2k+1]} bf16.
// Thread mapping: 256 thr = m(2) x colpair p(64) x rowhalf rh(2);
// each thread: 16 rows x 2 cols  (halves LDS read issue vs 1 col/thread).
// ---------------------------------------------------------------------------
#define TILE_R 32
__global__ __launch_bounds__(256) void gemm_kernel(
    const float* __restrict__ x,
    const float* __restrict__ Wm, const float* __restrict__ bm,
    const float* __restrict__ Ws, const float* __restrict__ bs,
    float* __restrict__ h, ushort2* __restrict__ hpk)
{
    __shared__ float xs[TILE_R][D];
    const int r0 = blockIdx.x * TILE_R;
    const int tid = threadIdx.x;

    // stage x tile: 32x128 floats, float4-vectorized, coalesced
    for (int i = tid; i < TILE_R * D / 4; i += 256) {
        int rr = i / (D / 4);
        int cc = (i % (D / 4)) * 4;
        int r = r0 + rr;
        float4 v = make_float4(0.f, 0.f, 0.f, 0.f);
        if (r < N_NODES) v = *(const float4*)(x + (size_t)r * D + cc);
        *(float4*)(&xs[rr][cc]) = v;
    }
    __syncthreads();

    const int m = tid >> 7;              // 0 = mean, 1 = std
    const int p = (tid >> 1) & 63;       // column pair index
    const int rh = tid & 1;              // row half (16 rows each)
    const int c0 = p * 2;
    const float* __restrict__ W = m ? Ws : Wm;
    const float* __restrict__ b = m ? bs : bm;
    const float b0 = b[c0], b1 = b[c0 + 1];

    float acc0[16], acc1[16];
#pragma unroll
    for (int rr = 0; rr < 16; ++rr) { acc0[rr] = b0; acc1[rr] = b1; }

    const float* __restrict__ Wr0 = W + (size_t)c0 * D;
    const float* __restrict__ Wr1 = W + (size_t)(c0 + 1) * D;

    for (int kc = 0; kc < D; kc += 32) {
        float w0[32], w1[32];
#pragma unroll
        for (int j = 0; j < 32; j += 4) {
            float4 a = *(const float4*)(Wr0 + kc + j);
            float4 bb = *(const float4*)(Wr1 + kc + j);
            w0[j] = a.x; w0[j+1] = a.y; w0[j+2] = a.z; w0[j+3] = a.w;
            w1[j] = bb.x; w1[j+1] = bb.y; w1[j+2] = bb.z; w1[j+3] = bb.w;
        }
#pragma unroll
        for (int rr = 0; rr < 16; ++rr) {
            const float* xr = &xs[rh * 16 + rr][kc];
#pragma unroll
            for (int j = 0; j < 32; j += 4) {
                float4 xv = *(const float4*)(xr + j);   // LDS b128, wave-broadcast
                acc0[rr] = fmaf(xv.x, w0[j],     acc0[rr]);
                acc0[rr] = fmaf(xv.y, w0[j + 1], acc0[rr]);
                acc0[rr] = fmaf(xv.z, w0[j + 2], acc0[rr]);
                acc0[rr] = fmaf(xv.w, w0[j + 3], acc0[rr]);
                acc1[rr] = fmaf(xv.x, w1[j],     acc1[rr]);
                acc1[rr] = fmaf(xv.y, w1[j + 1], acc1[rr]);
                acc1[rr] = fmaf(xv.z, w1[j + 2], acc1[rr]);
                acc1[rr] = fmaf(xv.w, w1[j + 3], acc1[rr]);
            }
        }
    }

    const size_t hb = (size_t)m * N_NODES * D;
#pragma unroll
    for (int rr = 0; rr < 16; ++rr) {
        int r = r0 + rh * 16 + rr;
        if (r < N_NODES) {
            float2 v; v.x = acc0[rr]; v.y = acc1[rr];
            *(float2*)(h + hb + (size_t)r * D + c0) = v;
            // packed bf16: byte off = r*512 + p*8 + m*4
            ushort2 u; u.x = f2bf(acc0[rr]); u.y = f2bf(acc1[rr]);
            hpk[(size_t)r * 128 + p * 2 + m] = u;
        }
    }
}

// ---------------------------------------------------------------------------
// CSR aggregation: ONE WAVE per node, lane = column pair (float2).
// Per edge: 2 loads (ea fp32 8B/lane, packed-bf16 h 8B/lane), metadata
// broadcast via readlane, 1-deep software pipeline (prefetch edge j+1
// while computing edge j) so loads stay in flight across edges. No atomics.
// ---------------------------------------------------------------------------
__global__ __launch_bounds__(256) void agg_kernel(
    const float* __restrict__ ea, const uint2* __restrict__ hpk,
    const int4* __restrict__ meta,
    const int* __restrict__ offset, const int* __restrict__ cur,
    const float* __restrict__ dis,
    const float* __restrict__ hm, const float* __restrict__ hs,
    float* __restrict__ om, float* __restrict__ os)
{
    const int tid = threadIdx.x;
    const int lane = tid & 63;
    const int wid = tid >> 6;
    const int n = blockIdx.x * 4 + wid;

    const int start = offset[n];
    const int end = cur[n];          // after scatter, cur[n] == segment end
    const float dc = dis[n];
    const int k = lane * 2;

    float amx = 0.f, amy = 0.f, asx = 0.f, asy = 0.f;

    for (int jb = start; jb < end; jb += 64) {
        int4 mt = make_int4(0, 0, 0, 0);
        if (jb + lane < end) mt = meta[jb + lane];
        const int mm = min(64, end - jb);

        // prime edge 0
        int e0   = __builtin_amdgcn_readlane(mt.x, 0);
        int row0 = __builtin_amdgcn_readlane(mt.y, 0);
        float dr_c = __int_as_float(__builtin_amdgcn_readlane(mt.z, 0));
        float2 ea_c = *(const float2*)(ea + (size_t)e0 * D + k);
        uint2  hp_c = hpk[(size_t)row0 * 64 + lane];

        for (int j = 0; j < mm; ++j) {
            // prefetch edge j+1 (clamped -> branchless, always valid)
            const int jn = (j + 1 < mm) ? (j + 1) : j;
            int e1   = __builtin_amdgcn_readlane(mt.x, jn);
            int row1 = __builtin_amdgcn_readlane(mt.y, jn);
            float dr_n = __int_as_float(__builtin_amdgcn_readlane(mt.z, jn));
            float2 ea_n = *(const float2*)(ea + (size_t)e1 * D + k);
            uint2  hp_n = hpk[(size_t)row1 * 64 + lane];

            // decode packed bf16: {hm2k, hm2k+1} in hp.x, {hs2k, hs2k+1} in hp.y
            float h0 = __uint_as_float(hp_c.x << 16);
            float h1 = __uint_as_float(hp_c.x & 0xFFFF0000u);
            float g0 = __uint_as_float(hp_c.y << 16);
            float g1 = __uint_as_float(hp_c.y & 0xFFFF0000u);

            amx = fmaf(dr_c, h0 + ea_c.x, amx);
            amy = fmaf(dr_c, h1 + ea_c.y, amy);
            asx = fmaf(dr_c, g0 + ea_c.x, asx);
            asy = fmaf(dr_c, g1 + ea_c.y, asy);

            ea_c = ea_n; hp_c = hp_n; dr_c = dr_n;
        }
    }

    const size_t ob = (size_t)n * D + k;
    float2 hmn = *(const float2*)(hm + ob);
    float2 hsn = *(const float2*)(hs + ob);
    float2 o0, o1;
    o0.x = hmn.x + dc * amx;  o0.y = hmn.y + dc * amy;
    o1.x = hsn.x + dc * asx;  o1.y = hsn.y + dc * asy;
    *(float2*)(om + ob) = o0;
    *(float2*)(os + ob) = o1;
}

extern "C" void kernel_launch(void* const* d_in, const int* in_sizes, int n_in,
                              void* d_out, int out_size, void* d_ws, size_t ws_size,
                              hipStream_t stream) {
    const float* x   = (const float*)d_in[0];
    const int*   ei  = (const int*)d_in[1];     // [2, E] int32
    const float* ea  = (const float*)d_in[2];   // [E, D]
    const float* Wm  = (const float*)d_in[3];
    const float* bm  = (const float*)d_in[4];
    const float* Ws  = (const float*)d_in[5];
    const float* bs  = (const float*)d_in[6];
    float* out = (float*)d_out;                 // [2, N, D]

    // workspace layout (16B-aligned chunks)
    char* w = (char*)d_ws;
    int*   count  = (int*)w;     w += (size_t)N_NODES * 4;   // 200000 B
    int*   offset = (int*)w;     w += (size_t)N_NODES * 4;
    int*   cur    = (int*)w;     w += (size_t)N_NODES * 4;
    float* dis    = (float*)w;   w += (size_t)N_NODES * 4;
    int*   bsum   = (int*)w;     w += 4096;                  // 49 used, padded
    int4*  meta   = (int4*)w;    w += (size_t)N_EDGES * 16;  // 12.8 MB
    float* h      = (float*)w;   w += (size_t)2 * N_NODES * D * 4;  // 51.2 MB
    ushort2* hpk  = (ushort2*)w;                             // 25.6 MB packed bf16
    float* hm = h;
    float* hs = h + (size_t)N_NODES * D;

    float* om = out;
    float* os = out + (size_t)N_NODES * D;

    const int SCAN_BLKS = (N_NODES + 1023) / 1024;   // 49

    // 1. zero histogram
    zero_kernel<<<(N_NODES + 255) / 256, 256, 0, stream>>>(count, N_NODES);

    // 2. histogram of destinations
    hist_kernel<<<(N_EDGES + 255) / 256, 256, 0, stream>>>(ei, count);

    // 3-4. parallel exclusive scan (+ dis = rsqrt(deg) fused)
    scan1_kernel<<<SCAN_BLKS, 1024, 0, stream>>>(count, offset, dis, bsum);
    fixup_kernel<<<SCAN_BLKS, 1024, 0, stream>>>(bsum, offset, cur);

    // 5. counting-sort scatter of packed edge metadata
    scatter_kernel<<<(N_EDGES + 255) / 256, 256, 0, stream>>>(ei, dis, cur, meta);

    // 6. linear projections -> fp32 h + packed bf16 hpk
    gemm_kernel<<<(N_NODES + TILE_R - 1) / TILE_R, 256, 0, stream>>>(
        x, Wm, bm, Ws, bs, h, (ushort2*)hpk);

    // 7. atomic-free CSR aggregation: one wave per node, pipelined
    agg_kernel<<<N_NODES / 4, 256, 0, stream>>>(ea, (const uint2*)hpk, meta,
                                                offset, cur, dis, hm, hs, om, os);
}

// Round 5
// 267.823 us; speedup vs baseline: 5.4629x; 1.1242x over previous
//
#include <hip/hip_runtime.h>
#include <math.h>

#define N_NODES 50000
#define N_EDGES 800000
#define D 128

typedef float        vf2 __attribute__((ext_vector_type(2)));
typedef unsigned int vu2 __attribute__((ext_vector_type(2)));
typedef int          vi4 __attribute__((ext_vector_type(4)));

// round-to-nearest-even fp32 -> bf16 (values are finite)
static __device__ __forceinline__ unsigned short f2bf(float f) {
    unsigned u = __float_as_uint(f);
    u += 0x7FFFu + ((u >> 16) & 1u);
    return (unsigned short)(u >> 16);
}

// ---------------------------------------------------------------------------
// count[col[e]]++  (int histogram of destination nodes)
// ---------------------------------------------------------------------------
__global__ __launch_bounds__(256) void hist_kernel(const int* __restrict__ ei,
                                                   int* __restrict__ count) {
    int e = blockIdx.x * blockDim.x + threadIdx.x;
    if (e < N_EDGES) {
        atomicAdd(&count[ei[N_EDGES + e]], 1);
    }
}

// ---------------------------------------------------------------------------
// scan1: per-block (1024-element) exclusive scan of count -> offset (local),
// block totals -> bsum, and dis = rsqrt(count) fused in.
// ---------------------------------------------------------------------------
__global__ __launch_bounds__(1024) void scan1_kernel(const int* __restrict__ count,
                                                     int* __restrict__ offset,
                                                     float* __restrict__ dis,
                                                     int* __restrict__ bsum) {
    __shared__ int wsum[16];
    const int tid = threadIdx.x;
    const int lane = tid & 63;
    const int wid = tid >> 6;
    const int i = blockIdx.x * 1024 + tid;

    int c = (i < N_NODES) ? count[i] : 0;
    int inc = c;
#pragma unroll
    for (int d = 1; d < 64; d <<= 1) {
        int v = __shfl_up(inc, d, 64);
        if (lane >= d) inc += v;
    }
    if (lane == 63) wsum[wid] = inc;
    __syncthreads();
    if (wid == 0) {
        int s = (lane < 16) ? wsum[lane] : 0;
#pragma unroll
        for (int d = 1; d < 16; d <<= 1) {
            int v = __shfl_up(s, d, 64);
            if (lane >= d) s += v;
        }
        if (lane < 16) wsum[lane] = s;   // inclusive wave-prefix
    }
    __syncthreads();
    int wpre = (wid > 0) ? wsum[wid - 1] : 0;
    if (i < N_NODES) {
        offset[i] = wpre + inc - c;       // block-local exclusive prefix
        dis[i] = (c > 0) ? rsqrtf((float)c) : 0.0f;
    }
    if (tid == 0) bsum[blockIdx.x] = wsum[15];
}

// ---------------------------------------------------------------------------
// fixup: offset[i] += sum(bsum[0..blk)); cur[i] = offset[i]
// ---------------------------------------------------------------------------
__global__ __launch_bounds__(1024) void fixup_kernel(const int* __restrict__ bsum,
                                                     int* __restrict__ offset,
                                                     int* __restrict__ cur) {
    __shared__ int pre_s;
    const int tid = threadIdx.x;
    const int blk = blockIdx.x;
    if ((tid >> 6) == 0) {
        int lane = tid & 63;
        int s = 0;
        for (int j = lane; j < blk; j += 64) s += bsum[j];
#pragma unroll
        for (int d = 32; d > 0; d >>= 1) s += __shfl_xor(s, d, 64);
        if (lane == 0) pre_s = s;
    }
    __syncthreads();
    int i = blk * 1024 + tid;
    if (i < N_NODES) {
        int o = offset[i] + pre_s;
        offset[i] = o;
        cur[i] = o;
    }
}

// ---------------------------------------------------------------------------
// FUSED: gemm (blocks [0, GEMM_BLKS)) || counting-sort scatter (rest).
// gemm is VALU-bound, scatter is memory-latency-bound -> complementary pipes.
//
// gemm: h_mean = x @ Wm^T + bm ; h_std = x @ Ws^T + bs.
//   Writes fp32 h (residual source) AND packed bf16 hpk (gather source):
//   hpk byte layout per row r: k-pair p=0..63 : {hm[2p],hm[2p+1],hs[2p],hs[2p+1]}.
// scatter: meta[cur[col]++] = { e, row, bitcast(dis[row]), 0 }
// ---------------------------------------------------------------------------
#define TILE_R 32
#define GEMM_BLKS ((N_NODES + TILE_R - 1) / TILE_R)          // 1563
#define SCAT_BLKS ((N_EDGES + 255) / 256)                    // 3125
__global__ __launch_bounds__(256) void fused_kernel(
    const float* __restrict__ x,
    const float* __restrict__ Wm, const float* __restrict__ bm,
    const float* __restrict__ Ws, const float* __restrict__ bs,
    float* __restrict__ h, ushort2* __restrict__ hpk,
    const int* __restrict__ ei, const float* __restrict__ dis,
    int* __restrict__ cur, int4* __restrict__ meta)
{
    __shared__ float xs[TILE_R][D];
    const int tid = threadIdx.x;

    if (blockIdx.x >= GEMM_BLKS) {
        // ---------------- scatter part ----------------
        int e = (blockIdx.x - GEMM_BLKS) * 256 + tid;
        if (e < N_EDGES) {
            int row = ei[e];
            int col = ei[N_EDGES + e];
            int p = atomicAdd(&cur[col], 1);
            meta[p] = make_int4(e, row, __float_as_int(dis[row]), 0);
        }
        return;
    }

    // ---------------- gemm part ----------------
    const int r0 = blockIdx.x * TILE_R;

    for (int i = tid; i < TILE_R * D / 4; i += 256) {
        int rr = i / (D / 4);
        int cc = (i % (D / 4)) * 4;
        int r = r0 + rr;
        float4 v = make_float4(0.f, 0.f, 0.f, 0.f);
        if (r < N_NODES) v = *(const float4*)(x + (size_t)r * D + cc);
        *(float4*)(&xs[rr][cc]) = v;
    }
    __syncthreads();

    const int m = tid >> 7;              // 0 = mean, 1 = std
    const int p = (tid >> 1) & 63;       // column pair index
    const int rh = tid & 1;              // row half (16 rows each)
    const int c0 = p * 2;
    const float* __restrict__ W = m ? Ws : Wm;
    const float* __restrict__ b = m ? bs : bm;
    const float b0 = b[c0], b1 = b[c0 + 1];

    float acc0[16], acc1[16];
#pragma unroll
    for (int rr = 0; rr < 16; ++rr) { acc0[rr] = b0; acc1[rr] = b1; }

    const float* __restrict__ Wr0 = W + (size_t)c0 * D;
    const float* __restrict__ Wr1 = W + (size_t)(c0 + 1) * D;

    for (int kc = 0; kc < D; kc += 32) {
        float w0[32], w1[32];
#pragma unroll
        for (int j = 0; j < 32; j += 4) {
            float4 a = *(const float4*)(Wr0 + kc + j);
            float4 bb = *(const float4*)(Wr1 + kc + j);
            w0[j] = a.x; w0[j+1] = a.y; w0[j+2] = a.z; w0[j+3] = a.w;
            w1[j] = bb.x; w1[j+1] = bb.y; w1[j+2] = bb.z; w1[j+3] = bb.w;
        }
#pragma unroll
        for (int rr = 0; rr < 16; ++rr) {
            const float* xr = &xs[rh * 16 + rr][kc];
#pragma unroll
            for (int j = 0; j < 32; j += 4) {
                float4 xv = *(const float4*)(xr + j);   // LDS b128, broadcast
                acc0[rr] = fmaf(xv.x, w0[j],     acc0[rr]);
                acc0[rr] = fmaf(xv.y, w0[j + 1], acc0[rr]);
                acc0[rr] = fmaf(xv.z, w0[j + 2], acc0[rr]);
                acc0[rr] = fmaf(xv.w, w0[j + 3], acc0[rr]);
                acc1[rr] = fmaf(xv.x, w1[j],     acc1[rr]);
                acc1[rr] = fmaf(xv.y, w1[j + 1], acc1[rr]);
                acc1[rr] = fmaf(xv.z, w1[j + 2], acc1[rr]);
                acc1[rr] = fmaf(xv.w, w1[j + 3], acc1[rr]);
            }
        }
    }

    const size_t hb = (size_t)m * N_NODES * D;
#pragma unroll
    for (int rr = 0; rr < 16; ++rr) {
        int r = r0 + rh * 16 + rr;
        if (r < N_NODES) {
            float2 v; v.x = acc0[rr]; v.y = acc1[rr];
            *(float2*)(h + hb + (size_t)r * D + c0) = v;
            ushort2 u; u.x = f2bf(acc0[rr]); u.y = f2bf(acc1[rr]);
            hpk[(size_t)r * 128 + p * 2 + m] = u;
        }
    }
}

// ---------------------------------------------------------------------------
// CSR aggregation: ONE WAVE per node, lane = column pair.
// All single-touch streams (meta, ea, residual, output) are NONTEMPORAL so
// L3 retains the reused hpk gather buffer (25.6 MB). 2-deep software
// pipeline (prefetch edge j+2) keeps >=6 loads in flight per wave.
// ---------------------------------------------------------------------------
__global__ __launch_bounds__(256) void agg_kernel(
    const float* __restrict__ ea, const vu2* __restrict__ hpk,
    const int4* __restrict__ meta,
    const int* __restrict__ offset, const int* __restrict__ cur,
    const float* __restrict__ dis,
    const float* __restrict__ hm, const float* __restrict__ hs,
    float* __restrict__ om, float* __restrict__ os)
{
    const int tid = threadIdx.x;
    const int lane = tid & 63;
    const int wid = tid >> 6;
    const int n = blockIdx.x * 4 + wid;

    const int start = offset[n];
    const int end = cur[n];          // after scatter, cur[n] == segment end
    const float dc = dis[n];
    const int k = lane * 2;

    // residual rows: issue early, consumed at the end (nontemporal)
    const size_t ob = (size_t)n * D + k;
    vf2 hmn = __builtin_nontemporal_load((const vf2*)(hm + ob));
    vf2 hsn = __builtin_nontemporal_load((const vf2*)(hs + ob));

    float amx = 0.f, amy = 0.f, asx = 0.f, asy = 0.f;

    for (int jb = start; jb < end; jb += 64) {
        vi4 mt = (vi4)(0);
        if (jb + lane < end)
            mt = __builtin_nontemporal_load((const vi4*)(meta + jb + lane));
        const int mm = min(64, end - jb);

        // prime slots A (j) and B (j+1), clamped
        int   eA = __builtin_amdgcn_readlane(mt[0], 0);
        int   rA = __builtin_amdgcn_readlane(mt[1], 0);
        float dA = __int_as_float(__builtin_amdgcn_readlane(mt[2], 0));
        vf2 eaA = __builtin_nontemporal_load((const vf2*)(ea + (size_t)eA * D + k));
        vu2 hpA = hpk[(size_t)rA * 64 + lane];

        const int j1 = (mm > 1) ? 1 : 0;
        int   eB = __builtin_amdgcn_readlane(mt[0], j1);
        int   rB = __builtin_amdgcn_readlane(mt[1], j1);
        float dB = __int_as_float(__builtin_amdgcn_readlane(mt[2], j1));
        vf2 eaB = __builtin_nontemporal_load((const vf2*)(ea + (size_t)eB * D + k));
        vu2 hpB = hpk[(size_t)rB * 64 + lane];

        for (int j = 0; j < mm; ++j) {
            // prefetch edge j+2 (clamped -> branchless, always valid)
            const int jn = (j + 2 < mm) ? (j + 2) : (mm - 1);
            int   eN = __builtin_amdgcn_readlane(mt[0], jn);
            int   rN = __builtin_amdgcn_readlane(mt[1], jn);
            float dN = __int_as_float(__builtin_amdgcn_readlane(mt[2], jn));
            vf2 eaN = __builtin_nontemporal_load((const vf2*)(ea + (size_t)eN * D + k));
            vu2 hpN = hpk[(size_t)rN * 64 + lane];

            // decode packed bf16 slot A: {hm2k,hm2k+1} in hpA[0], {hs...} in hpA[1]
            float h0 = __uint_as_float(hpA[0] << 16);
            float h1 = __uint_as_float(hpA[0] & 0xFFFF0000u);
            float g0 = __uint_as_float(hpA[1] << 16);
            float g1 = __uint_as_float(hpA[1] & 0xFFFF0000u);

            amx = fmaf(dA, h0 + eaA[0], amx);
            amy = fmaf(dA, h1 + eaA[1], amy);
            asx = fmaf(dA, g0 + eaA[0], asx);
            asy = fmaf(dA, g1 + eaA[1], asy);

            eaA = eaB; hpA = hpB; dA = dB;
            eaB = eaN; hpB = hpN; dB = dN;
        }
    }

    vf2 o0, o1;
    o0[0] = hmn[0] + dc * amx;  o0[1] = hmn[1] + dc * amy;
    o1[0] = hsn[0] + dc * asx;  o1[1] = hsn[1] + dc * asy;
    __builtin_nontemporal_store(o0, (vf2*)(om + ob));
    __builtin_nontemporal_store(o1, (vf2*)(os + ob));
}

extern "C" void kernel_launch(void* const* d_in, const int* in_sizes, int n_in,
                              void* d_out, int out_size, void* d_ws, size_t ws_size,
                              hipStream_t stream) {
    const float* x   = (const float*)d_in[0];
    const int*   ei  = (const int*)d_in[1];     // [2, E] int32
    const float* ea  = (const float*)d_in[2];   // [E, D]
    const float* Wm  = (const float*)d_in[3];
    const float* bm  = (const float*)d_in[4];
    const float* Ws  = (const float*)d_in[5];
    const float* bs  = (const float*)d_in[6];
    float* out = (float*)d_out;                 // [2, N, D]

    // workspace layout (16B-aligned chunks)
    char* w = (char*)d_ws;
    int*   count  = (int*)w;     w += (size_t)N_NODES * 4;
    int*   offset = (int*)w;     w += (size_t)N_NODES * 4;
    int*   cur    = (int*)w;     w += (size_t)N_NODES * 4;
    float* dis    = (float*)w;   w += (size_t)N_NODES * 4;
    int*   bsum   = (int*)w;     w += 4096;
    int4*  meta   = (int4*)w;    w += (size_t)N_EDGES * 16;        // 12.8 MB
    float* h      = (float*)w;   w += (size_t)2 * N_NODES * D * 4; // 51.2 MB
    ushort2* hpk  = (ushort2*)w;                                   // 25.6 MB
    float* hm = h;
    float* hs = h + (size_t)N_NODES * D;

    float* om = out;
    float* os = out + (size_t)N_NODES * D;

    const int SCAN_BLKS = (N_NODES + 1023) / 1024;   // 49

    // 1. zero histogram (ws poisoned 0xAA once, never re-poisoned)
    hipMemsetAsync(count, 0, N_NODES * sizeof(int), stream);

    // 2. histogram of destinations
    hist_kernel<<<SCAT_BLKS, 256, 0, stream>>>(ei, count);

    // 3-4. parallel exclusive scan (+ dis = rsqrt(deg) fused)
    scan1_kernel<<<SCAN_BLKS, 1024, 0, stream>>>(count, offset, dis, bsum);
    fixup_kernel<<<SCAN_BLKS, 1024, 0, stream>>>(bsum, offset, cur);

    // 5. gemm || scatter (independent; complementary pipes)
    fused_kernel<<<GEMM_BLKS + SCAT_BLKS, 256, 0, stream>>>(
        x, Wm, bm, Ws, bs, h, hpk, ei, dis, cur, meta);

    // 6. atomic-free CSR aggregation: one wave per node, 2-deep pipeline, NT streams
    agg_kernel<<<N_NODES / 4, 256, 0, stream>>>(ea, (const vu2*)hpk, meta,
                                                offset, cur, dis, hm, hs, om, os);
}